// Round 1
// baseline (511.222 us; speedup 1.0000x reference)
//
#include <hip/hip_runtime.h>
#include <math.h>

// Problem constants (HeadAttention_738734374917)
#define Bn  8
#define Nn  2048
#define Dn  1024
#define DHn 64

// ---------------------------------------------------------------------------
// K1: fused QKV projection.  x[16384,1024] @ W[1024,192] (+bias), K scaled by
// 1/8 (fold the 1/sqrt(DH) into K').  Tile: 64 rows x 192 cols, BK=16.
// 256 threads: thread = (rt 0..15 -> 4 rows, ct 0..15 -> 12 cols).
// ---------------------------------------------------------------------------
__global__ __launch_bounds__(256) void qkv_kernel(
    const float* __restrict__ x,
    const float* __restrict__ Wq, const float* __restrict__ bq,
    const float* __restrict__ Wk, const float* __restrict__ bk,
    const float* __restrict__ Wv, const float* __restrict__ bv,
    float* __restrict__ Q, float* __restrict__ K, float* __restrict__ V)
{
    __shared__ float xs[16][64];    // [k][row]  (transposed for f4 compute reads)
    __shared__ float wsh[16][192];  // [k][col]

    const int t = threadIdx.x;
    const int rowbase = blockIdx.x * 64;
    const int ct = t & 15;   // col group: cols ct*12 .. ct*12+11
    const int rt = t >> 4;   // row group: rows rt*4 .. rt*4+3

    float acc[4][12];
#pragma unroll
    for (int i = 0; i < 4; ++i)
#pragma unroll
        for (int j = 0; j < 12; ++j) acc[i][j] = 0.f;

    for (int kt = 0; kt < Dn / 16; ++kt) {
        const int k0 = kt * 16;
        __syncthreads();
        // x tile: 64 rows x 16 k, store transposed xs[k][row]
        {
            const int row = t >> 2;   // 0..63
            const int kq  = t & 3;    // 0..3
            const float4 v = *reinterpret_cast<const float4*>(
                &x[(rowbase + row) * Dn + k0 + kq * 4]);
            xs[kq * 4 + 0][row] = v.x;
            xs[kq * 4 + 1][row] = v.y;
            xs[kq * 4 + 2][row] = v.z;
            xs[kq * 4 + 3][row] = v.w;
        }
        // W tile: 16 k x 192 cols (Q|K|V concatenated)
#pragma unroll
        for (int q = 0; q < 3; ++q) {
            const int f  = t + q * 256;  // float4 index 0..767
            const int kl = f / 48;       // 0..15
            const int c4 = f % 48;       // 0..47
            const int c  = c4 * 4;
            const float* Wm = (c < 64) ? Wq : (c < 128 ? Wk : Wv);
            const int cm = c & 63;
            const float4 v = *reinterpret_cast<const float4*>(
                &Wm[(k0 + kl) * DHn + cm]);
            *reinterpret_cast<float4*>(&wsh[kl][c4 * 4]) = v;
        }
        __syncthreads();
#pragma unroll
        for (int k = 0; k < 16; ++k) {
            const float4 xa  = *reinterpret_cast<const float4*>(&xs[k][rt * 4]);
            const float4 wb0 = *reinterpret_cast<const float4*>(&wsh[k][ct * 12 + 0]);
            const float4 wb1 = *reinterpret_cast<const float4*>(&wsh[k][ct * 12 + 4]);
            const float4 wb2 = *reinterpret_cast<const float4*>(&wsh[k][ct * 12 + 8]);
            const float xr[4]  = {xa.x, xa.y, xa.z, xa.w};
            const float wr[12] = {wb0.x, wb0.y, wb0.z, wb0.w,
                                  wb1.x, wb1.y, wb1.z, wb1.w,
                                  wb2.x, wb2.y, wb2.z, wb2.w};
#pragma unroll
            for (int i = 0; i < 4; ++i)
#pragma unroll
                for (int j = 0; j < 12; ++j)
                    acc[i][j] = fmaf(xr[i], wr[j], acc[i][j]);
        }
    }
    // epilogue: bias, K-scale, store
#pragma unroll
    for (int i = 0; i < 4; ++i) {
        const int row = rowbase + rt * 4 + i;
#pragma unroll
        for (int j4 = 0; j4 < 3; ++j4) {
            const int c  = ct * 12 + j4 * 4;
            const int m  = c >> 6;   // 0=Q, 1=K, 2=V (4-col group never crosses 64)
            const int cm = c & 63;
            const float* bias = (m == 0) ? bq : ((m == 1) ? bk : bv);
            float* Out        = (m == 0) ? Q  : ((m == 1) ? K  : V);
            const float s = (m == 1) ? 0.125f : 1.0f;  // fold 1/sqrt(64) into K
            float4 o;
            o.x = (acc[i][j4 * 4 + 0] + bias[cm + 0]) * s;
            o.y = (acc[i][j4 * 4 + 1] + bias[cm + 1]) * s;
            o.z = (acc[i][j4 * 4 + 2] + bias[cm + 2]) * s;
            o.w = (acc[i][j4 * 4 + 3] + bias[cm + 3]) * s;
            *reinterpret_cast<float4*>(&Out[row * DHn + cm]) = o;
        }
    }
}

// ---------------------------------------------------------------------------
// K2: column sums  l[j] = sum_i exp(Q_i . K'_j)   (softmax is over the i axis)
// Block = (batch, 64-column tile).  K tile resident in LDS (XOR-swizzled),
// loop i in chunks of 128.  Thread micro-tile: 8 i x 4 j.
// ---------------------------------------------------------------------------
__global__ __launch_bounds__(256) void colsum_kernel(
    const float* __restrict__ Q, const float* __restrict__ K,
    float* __restrict__ l)
{
    __shared__ float Ks[64][64];   // [j][d], d float4-swizzled by (j>>2)&7
    __shared__ float Qs[128][64];  // [i][d]
    __shared__ float red[16][64];

    const int t = threadIdx.x;
    const int b  = blockIdx.x >> 5;
    const int jt = blockIdx.x & 31;
    const int jbase = jt * 64;
    const int ct = t & 15;   // -> 4 j's
    const int rt = t >> 4;   // -> 8 i's

    // load K' tile once, swizzled
#pragma unroll
    for (int q = 0; q < 4; ++q) {
        const int jl = (t >> 4) + q * 16;
        const int c4 = t & 15;
        const float4 v = *reinterpret_cast<const float4*>(
            &K[(b * Nn + jbase + jl) * DHn + c4 * 4]);
        const int sw = c4 ^ ((jl >> 2) & 7);
        *reinterpret_cast<float4*>(&Ks[jl][sw * 4]) = v;
    }

    float acc_l[4] = {0.f, 0.f, 0.f, 0.f};

    for (int ic = 0; ic < Nn / 128; ++ic) {
        __syncthreads();  // prev-iter Qs reads done (also makes Ks visible, ic=0)
#pragma unroll
        for (int q = 0; q < 8; ++q) {
            const int rl = (t >> 4) + q * 16;
            const int c4 = t & 15;
            const float4 v = *reinterpret_cast<const float4*>(
                &Q[(b * Nn + ic * 128 + rl) * DHn + c4 * 4]);
            *reinterpret_cast<float4*>(&Qs[rl][c4 * 4]) = v;
        }
        __syncthreads();

        float acc_s[8][4];
#pragma unroll
        for (int i = 0; i < 8; ++i)
#pragma unroll
            for (int j = 0; j < 4; ++j) acc_s[i][j] = 0.f;

#pragma unroll
        for (int dc = 0; dc < 16; ++dc) {
            float4 qa[8], kb[4];
#pragma unroll
            for (int i = 0; i < 8; ++i)
                qa[i] = *reinterpret_cast<const float4*>(&Qs[rt * 8 + i][dc * 4]);
            const int sw = dc ^ (ct & 7);
#pragma unroll
            for (int j = 0; j < 4; ++j)
                kb[j] = *reinterpret_cast<const float4*>(&Ks[ct * 4 + j][sw * 4]);
#pragma unroll
            for (int i = 0; i < 8; ++i)
#pragma unroll
                for (int j = 0; j < 4; ++j)
                    acc_s[i][j] = fmaf(qa[i].x, kb[j].x,
                                  fmaf(qa[i].y, kb[j].y,
                                  fmaf(qa[i].z, kb[j].z,
                                  fmaf(qa[i].w, kb[j].w, acc_s[i][j]))));
        }
#pragma unroll
        for (int i = 0; i < 8; ++i)
#pragma unroll
            for (int j = 0; j < 4; ++j)
                acc_l[j] += __expf(acc_s[i][j]);
    }

    __syncthreads();
#pragma unroll
    for (int j = 0; j < 4; ++j) red[rt][ct * 4 + j] = acc_l[j];
    __syncthreads();
    if (t < 64) {
        float s = 0.f;
#pragma unroll
        for (int r = 0; r < 16; ++r) s += red[r][t];
        l[b * Nn + jbase + t] = s;
    }
}

// ---------------------------------------------------------------------------
// K3: out[b, i, :] = sum_j exp(Q_i . K'_j) * (V[j,:] / l_j)
// Block = (batch, 64-row tile).  Loop j in tiles of 64: recompute S-tile,
// exp -> Es (LDS), then acc_o += Es @ Vs'.  Thread micro-tiles 4x4.
// ---------------------------------------------------------------------------
__global__ __launch_bounds__(256) void attnout_kernel(
    const float* __restrict__ Q, const float* __restrict__ K,
    const float* __restrict__ V, const float* __restrict__ l,
    float* __restrict__ out)
{
    __shared__ float Qs[64][64];  // [i][d]
    __shared__ float Ks[64][64];  // [j][d], swizzled
    __shared__ float Vs[64][64];  // [j][d], pre-scaled by 1/l_j
    __shared__ float Es[64][64];  // [i][j]

    const int t = threadIdx.x;
    const int b  = blockIdx.x >> 5;
    const int it = blockIdx.x & 31;
    const int ibase = it * 64;
    const int ct = t & 15;
    const int rt = t >> 4;

    // Q tile, resident all kernel
#pragma unroll
    for (int q = 0; q < 4; ++q) {
        const int rl = (t >> 4) + q * 16;
        const int c4 = t & 15;
        const float4 v = *reinterpret_cast<const float4*>(
            &Q[(b * Nn + ibase + rl) * DHn + c4 * 4]);
        *reinterpret_cast<float4*>(&Qs[rl][c4 * 4]) = v;
    }

    float acc_o[4][4];
#pragma unroll
    for (int i = 0; i < 4; ++i)
#pragma unroll
        for (int d = 0; d < 4; ++d) acc_o[i][d] = 0.f;

    for (int jt2 = 0; jt2 < Nn / 64; ++jt2) {
        const int jbase = jt2 * 64;
        __syncthreads();  // prev-iter Es/Vs/Ks reads done; Qs visible (jt2=0)
#pragma unroll
        for (int q = 0; q < 4; ++q) {
            const int jl = (t >> 4) + q * 16;
            const int c4 = t & 15;
            const float4 kv = *reinterpret_cast<const float4*>(
                &K[(b * Nn + jbase + jl) * DHn + c4 * 4]);
            const int sw = c4 ^ ((jl >> 2) & 7);
            *reinterpret_cast<float4*>(&Ks[jl][sw * 4]) = kv;
            float4 vv = *reinterpret_cast<const float4*>(
                &V[(b * Nn + jbase + jl) * DHn + c4 * 4]);
            const float rl_ = 1.0f / l[b * Nn + jbase + jl];
            vv.x *= rl_; vv.y *= rl_; vv.z *= rl_; vv.w *= rl_;
            *reinterpret_cast<float4*>(&Vs[jl][c4 * 4]) = vv;
        }
        __syncthreads();

        // step a: S tile (4i x 4j per thread) + exp -> Es
        float acc_s[4][4];
#pragma unroll
        for (int i = 0; i < 4; ++i)
#pragma unroll
            for (int j = 0; j < 4; ++j) acc_s[i][j] = 0.f;
#pragma unroll
        for (int dc = 0; dc < 16; ++dc) {
            float4 qa[4], kb[4];
#pragma unroll
            for (int i = 0; i < 4; ++i)
                qa[i] = *reinterpret_cast<const float4*>(&Qs[rt * 4 + i][dc * 4]);
            const int sw = dc ^ (ct & 7);
#pragma unroll
            for (int j = 0; j < 4; ++j)
                kb[j] = *reinterpret_cast<const float4*>(&Ks[ct * 4 + j][sw * 4]);
#pragma unroll
            for (int i = 0; i < 4; ++i)
#pragma unroll
                for (int j = 0; j < 4; ++j)
                    acc_s[i][j] = fmaf(qa[i].x, kb[j].x,
                                  fmaf(qa[i].y, kb[j].y,
                                  fmaf(qa[i].z, kb[j].z,
                                  fmaf(qa[i].w, kb[j].w, acc_s[i][j]))));
        }
#pragma unroll
        for (int i = 0; i < 4; ++i) {
            float4 e;
            e.x = __expf(acc_s[i][0]);
            e.y = __expf(acc_s[i][1]);
            e.z = __expf(acc_s[i][2]);
            e.w = __expf(acc_s[i][3]);
            *reinterpret_cast<float4*>(&Es[rt * 4 + i][ct * 4]) = e;
        }
        __syncthreads();

        // step b: acc_o (4i x 4d) += Es @ Vs'
#pragma unroll
        for (int jc = 0; jc < 16; ++jc) {
            float4 ea[4], vb[4];
#pragma unroll
            for (int i = 0; i < 4; ++i)
                ea[i] = *reinterpret_cast<const float4*>(&Es[rt * 4 + i][jc * 4]);
#pragma unroll
            for (int j = 0; j < 4; ++j)
                vb[j] = *reinterpret_cast<const float4*>(&Vs[jc * 4 + j][ct * 4]);
#pragma unroll
            for (int i = 0; i < 4; ++i) {
                const float er[4] = {ea[i].x, ea[i].y, ea[i].z, ea[i].w};
#pragma unroll
                for (int j = 0; j < 4; ++j) {
                    acc_o[i][0] = fmaf(er[j], vb[j].x, acc_o[i][0]);
                    acc_o[i][1] = fmaf(er[j], vb[j].y, acc_o[i][1]);
                    acc_o[i][2] = fmaf(er[j], vb[j].z, acc_o[i][2]);
                    acc_o[i][3] = fmaf(er[j], vb[j].w, acc_o[i][3]);
                }
            }
        }
    }

#pragma unroll
    for (int i = 0; i < 4; ++i) {
        float4 o;
        o.x = acc_o[i][0]; o.y = acc_o[i][1];
        o.z = acc_o[i][2]; o.w = acc_o[i][3];
        *reinterpret_cast<float4*>(
            &out[(b * Nn + ibase + rt * 4 + i) * DHn + ct * 4]) = o;
    }
}

// ---------------------------------------------------------------------------
extern "C" void kernel_launch(void* const* d_in, const int* in_sizes, int n_in,
                              void* d_out, int out_size, void* d_ws, size_t ws_size,
                              hipStream_t stream)
{
    const float* x  = (const float*)d_in[0];
    const float* Wq = (const float*)d_in[1];
    const float* bq = (const float*)d_in[2];
    const float* Wk = (const float*)d_in[3];
    const float* bk = (const float*)d_in[4];
    const float* Wv = (const float*)d_in[5];
    const float* bv = (const float*)d_in[6];
    float* out = (float*)d_out;

    float* ws = (float*)d_ws;
    float* Q  = ws;                       // 16384 x 64
    float* K  = ws + (size_t)Bn * Nn * DHn;       // K' = K * 0.125
    float* V  = ws + (size_t)2 * Bn * Nn * DHn;
    float* lv = ws + (size_t)3 * Bn * Nn * DHn;   // column sums, B*N

    qkv_kernel<<<dim3((Bn * Nn) / 64), dim3(256), 0, stream>>>(
        x, Wq, bq, Wk, bk, Wv, bv, Q, K, V);
    colsum_kernel<<<dim3(Bn * (Nn / 64)), dim3(256), 0, stream>>>(Q, K, lv);
    attnout_kernel<<<dim3(Bn * (Nn / 64)), dim3(256), 0, stream>>>(Q, K, V, lv, out);
}

// Round 2
// 174.263 us; speedup vs baseline: 2.9336x; 2.9336x over previous
//
#include <hip/hip_runtime.h>
#include <math.h>

// Problem constants (HeadAttention_738734374917)
#define Bn  8
#define Nn  2048
#define Dn  1024
#define DHn 64

typedef __attribute__((ext_vector_type(8))) short bf16x8;  // 8 bf16 = 4 VGPRs
typedef __attribute__((ext_vector_type(4))) float f32x4;

static __device__ inline short f2bf(float f) {
    unsigned u = __builtin_bit_cast(unsigned, f);
    u += 0x7FFFu + ((u >> 16) & 1u);     // round-to-nearest-even
    return (short)(u >> 16);
}
static __device__ inline bf16x8 pack8(float4 a, float4 b) {
    bf16x8 v;
    v[0] = f2bf(a.x); v[1] = f2bf(a.y); v[2] = f2bf(a.z); v[3] = f2bf(a.w);
    v[4] = f2bf(b.x); v[5] = f2bf(b.y); v[6] = f2bf(b.z); v[7] = f2bf(b.w);
    return v;
}

// ---------------------------------------------------------------------------
// W transpose: Wt[col 0..191][k 0..1023] bf16, col = {Q|K|V} x 64.
// ---------------------------------------------------------------------------
__global__ __launch_bounds__(256) void wt_kernel(
    const float* __restrict__ Wq, const float* __restrict__ Wk,
    const float* __restrict__ Wv, short* __restrict__ Wt)
{
    const int gn = blockIdx.x;              // 0..191
    const float* Wm = (gn < 64) ? Wq : (gn < 128 ? Wk : Wv);
    const int n = gn & 63;
    const int t = threadIdx.x;
#pragma unroll
    for (int r = 0; r < 4; ++r) {
        const int k = t * 4 + r;
        Wt[gn * Dn + k] = f2bf(Wm[k * DHn + n]);
    }
}

// ---------------------------------------------------------------------------
// Zero out (1M floats) + l (16K floats) — harness re-poisons to 0xAA.
// 266240 float4 total -> 1040 blocks x 256.
// ---------------------------------------------------------------------------
__global__ __launch_bounds__(256) void zero_kernel(float* __restrict__ out,
                                                   float* __restrict__ l)
{
    const int id = blockIdx.x * 256 + threadIdx.x;
    const float4 z = make_float4(0.f, 0.f, 0.f, 0.f);
    if (id < 262144) ((float4*)out)[id] = z;
    else             ((float4*)l)[id - 262144] = z;
}

// ---------------------------------------------------------------------------
// K1: QKV projection via bf16 MFMA. M-tile 64 (block), N=192 (4 waves x 48),
// BK=64 with register-prefetched x staging. W-frags direct from global Wt.
// Outputs: Qb[i][d], Kb[j][d] (*0.125), Vt[b][d][j] (transposed) — all bf16.
// ---------------------------------------------------------------------------
__global__ __launch_bounds__(256) void qkv_kernel(
    const float* __restrict__ x, const short* __restrict__ Wt,
    const float* __restrict__ bq, const float* __restrict__ bk,
    const float* __restrict__ bv,
    short* __restrict__ Qb, short* __restrict__ Kb, short* __restrict__ Vt)
{
    __shared__ __attribute__((aligned(16))) short xs[64][72];

    const int t = threadIdx.x;
    const int w = t >> 6, lane = t & 63;
    const int c = lane & 15, quad = lane >> 4;
    const int rowbase = blockIdx.x * 64;
    const int r0 = t >> 3, kc = t & 7;      // staging: rows r0, r0+32, 16B chunk kc

    float4 pf[4];
    {
        const float* p0 = &x[(size_t)(rowbase + r0) * Dn + kc * 8];
        pf[0] = *(const float4*)p0; pf[1] = *(const float4*)(p0 + 4);
        const float* p1 = &x[(size_t)(rowbase + r0 + 32) * Dn + kc * 8];
        pf[2] = *(const float4*)p1; pf[3] = *(const float4*)(p1 + 4);
    }

    f32x4 acc[4][3];
#pragma unroll
    for (int mt = 0; mt < 4; ++mt)
#pragma unroll
        for (int nt = 0; nt < 3; ++nt) acc[mt][nt] = (f32x4){0.f, 0.f, 0.f, 0.f};

    for (int kt = 0; kt < 16; ++kt) {
        __syncthreads();
        *(bf16x8*)&xs[r0][kc * 8]      = pack8(pf[0], pf[1]);
        *(bf16x8*)&xs[r0 + 32][kc * 8] = pack8(pf[2], pf[3]);
        __syncthreads();
        if (kt < 15) {
            const int k0n = (kt + 1) * 64;
            const float* p0 = &x[(size_t)(rowbase + r0) * Dn + k0n + kc * 8];
            pf[0] = *(const float4*)p0; pf[1] = *(const float4*)(p0 + 4);
            const float* p1 = &x[(size_t)(rowbase + r0 + 32) * Dn + k0n + kc * 8];
            pf[2] = *(const float4*)p1; pf[3] = *(const float4*)(p1 + 4);
        }
        const int k0 = kt * 64;
#pragma unroll
        for (int kk = 0; kk < 2; ++kk) {
            bf16x8 bfr[3];
#pragma unroll
            for (int nt = 0; nt < 3; ++nt)
                bfr[nt] = *(const bf16x8*)&Wt[(size_t)(w * 48 + nt * 16 + c) * Dn
                                              + k0 + kk * 32 + quad * 8];
#pragma unroll
            for (int mt = 0; mt < 4; ++mt) {
                const bf16x8 af = *(const bf16x8*)&xs[mt * 16 + c][kk * 32 + quad * 8];
#pragma unroll
                for (int nt = 0; nt < 3; ++nt)
                    acc[mt][nt] = __builtin_amdgcn_mfma_f32_16x16x32_bf16(
                        af, bfr[nt], acc[mt][nt], 0, 0, 0);
            }
        }
    }

#pragma unroll
    for (int nt = 0; nt < 3; ++nt) {
        const int col = w * 48 + nt * 16 + c;
        const int mat = col >> 6, cm = col & 63;   // mat uniform per (w,nt)
        const float bias = (mat == 0 ? bq : (mat == 1 ? bk : bv))[cm];
#pragma unroll
        for (int mt = 0; mt < 4; ++mt) {
#pragma unroll
            for (int r = 0; r < 4; ++r) {
                const int row = rowbase + mt * 16 + quad * 4 + r;
                const float o = acc[mt][nt][r] + bias;
                if (mat == 0)      Qb[(size_t)row * DHn + cm] = f2bf(o);
                else if (mat == 1) Kb[(size_t)row * DHn + cm] = f2bf(o * 0.125f);
                else {
                    const int b = row >> 11, i = row & (Nn - 1);
                    Vt[((size_t)b * DHn + cm) * Nn + i] = f2bf(o);
                }
            }
        }
    }
}

// ---------------------------------------------------------------------------
// K2: l[j] = sum_i exp(Q_i . K'_j).  Block = (b, j-tile 64, i-half).
// S via MFMA; exp on fp32 accs; LDS reduce; atomicAdd into zeroed l.
// ---------------------------------------------------------------------------
__global__ __launch_bounds__(256) void colsum_kernel(
    const short* __restrict__ Qb, const short* __restrict__ Kb,
    float* __restrict__ l)
{
    __shared__ __attribute__((aligned(16))) short Ks[64][72];
    __shared__ __attribute__((aligned(16))) short Qs[64][72];
    __shared__ float red[16][64];

    const int t = threadIdx.x;
    const int w = t >> 6, lane = t & 63;
    const int c = lane & 15, quad = lane >> 4;
    const int bid = blockIdx.x;
    const int b = bid >> 6, rem = bid & 63, jt = rem >> 1, half = rem & 1;
    const int jbase = jt * 64;
    const int r0 = t >> 3, kc = t & 7;

    *(bf16x8*)&Ks[r0][kc * 8]      = *(const bf16x8*)&Kb[((size_t)b * Nn + jbase + r0) * DHn + kc * 8];
    *(bf16x8*)&Ks[r0 + 32][kc * 8] = *(const bf16x8*)&Kb[((size_t)b * Nn + jbase + r0 + 32) * DHn + kc * 8];

    float lsum[4] = {0.f, 0.f, 0.f, 0.f};

    for (int it = 0; it < 16; ++it) {
        const int i0 = half * 1024 + it * 64;
        __syncthreads();   // Ks visible (it=0); prev-iter Qs reads done
        *(bf16x8*)&Qs[r0][kc * 8]      = *(const bf16x8*)&Qb[((size_t)b * Nn + i0 + r0) * DHn + kc * 8];
        *(bf16x8*)&Qs[r0 + 32][kc * 8] = *(const bf16x8*)&Qb[((size_t)b * Nn + i0 + r0 + 32) * DHn + kc * 8];
        __syncthreads();

        bf16x8 af0 = *(const bf16x8*)&Qs[w * 16 + c][quad * 8];
        bf16x8 af1 = *(const bf16x8*)&Qs[w * 16 + c][32 + quad * 8];
#pragma unroll
        for (int nt = 0; nt < 4; ++nt) {
            f32x4 s = (f32x4){0.f, 0.f, 0.f, 0.f};
            s = __builtin_amdgcn_mfma_f32_16x16x32_bf16(
                af0, *(const bf16x8*)&Ks[nt * 16 + c][quad * 8], s, 0, 0, 0);
            s = __builtin_amdgcn_mfma_f32_16x16x32_bf16(
                af1, *(const bf16x8*)&Ks[nt * 16 + c][32 + quad * 8], s, 0, 0, 0);
            lsum[nt] += __expf(s[0]) + __expf(s[1]) + __expf(s[2]) + __expf(s[3]);
        }
    }

#pragma unroll
    for (int nt = 0; nt < 4; ++nt) red[w * 4 + quad][nt * 16 + c] = lsum[nt];
    __syncthreads();
    if (t < 64) {
        float s = 0.f;
#pragma unroll
        for (int r = 0; r < 16; ++r) s += red[r][t];
        atomicAdd(&l[(size_t)b * Nn + jbase + t], s);
    }
}

// ---------------------------------------------------------------------------
// K3: out[i,:] += sum_j (exp(Q_i.K'_j)/l_j) V[j,:].  Block = (b, i-tile 64,
// j-half).  S MFMA -> exp*(1/l) -> wave-private Ps -> PV MFMA -> atomicAdd.
// ---------------------------------------------------------------------------
__global__ __launch_bounds__(256) void attnout_kernel(
    const short* __restrict__ Qb, const short* __restrict__ Kb,
    const short* __restrict__ Vt, const float* __restrict__ l,
    float* __restrict__ out)
{
    __shared__ __attribute__((aligned(16))) short Qs[64][72];
    __shared__ __attribute__((aligned(16))) short Ks[64][72];
    __shared__ __attribute__((aligned(16))) short Vst[64][72];  // [d][j]
    __shared__ __attribute__((aligned(16))) short Ps[4][16][72]; // wave-private
    __shared__ float rls[64];

    const int t = threadIdx.x;
    const int w = t >> 6, lane = t & 63;
    const int c = lane & 15, quad = lane >> 4;
    const int bid = blockIdx.x;
    const int b = bid >> 6, rem = bid & 63, it = rem >> 1, half = rem & 1;
    const int ibase = it * 64;
    const int r0 = t >> 3, kc = t & 7;

    *(bf16x8*)&Qs[r0][kc * 8]      = *(const bf16x8*)&Qb[((size_t)b * Nn + ibase + r0) * DHn + kc * 8];
    *(bf16x8*)&Qs[r0 + 32][kc * 8] = *(const bf16x8*)&Qb[((size_t)b * Nn + ibase + r0 + 32) * DHn + kc * 8];

    f32x4 acc[4];
#pragma unroll
    for (int dn = 0; dn < 4; ++dn) acc[dn] = (f32x4){0.f, 0.f, 0.f, 0.f};

    for (int jt2 = 0; jt2 < 16; ++jt2) {
        const int jb = half * 1024 + jt2 * 64;
        __syncthreads();   // Qs visible (jt2=0); prev-iter Ks/Vst/rls reads done
        *(bf16x8*)&Ks[r0][kc * 8]       = *(const bf16x8*)&Kb[((size_t)b * Nn + jb + r0) * DHn + kc * 8];
        *(bf16x8*)&Ks[r0 + 32][kc * 8]  = *(const bf16x8*)&Kb[((size_t)b * Nn + jb + r0 + 32) * DHn + kc * 8];
        *(bf16x8*)&Vst[r0][kc * 8]      = *(const bf16x8*)&Vt[((size_t)b * DHn + r0) * Nn + jb + kc * 8];
        *(bf16x8*)&Vst[r0 + 32][kc * 8] = *(const bf16x8*)&Vt[((size_t)b * DHn + r0 + 32) * Nn + jb + kc * 8];
        if (t < 64) rls[t] = 1.0f / l[(size_t)b * Nn + jb + t];
        __syncthreads();

        // S = Q.K'^T for this wave's 16 i-rows x 64 j
        bf16x8 aq0 = *(const bf16x8*)&Qs[w * 16 + c][quad * 8];
        bf16x8 aq1 = *(const bf16x8*)&Qs[w * 16 + c][32 + quad * 8];
#pragma unroll
        for (int nt = 0; nt < 4; ++nt) {
            f32x4 s = (f32x4){0.f, 0.f, 0.f, 0.f};
            s = __builtin_amdgcn_mfma_f32_16x16x32_bf16(
                aq0, *(const bf16x8*)&Ks[nt * 16 + c][quad * 8], s, 0, 0, 0);
            s = __builtin_amdgcn_mfma_f32_16x16x32_bf16(
                aq1, *(const bf16x8*)&Ks[nt * 16 + c][32 + quad * 8], s, 0, 0, 0);
            const float rl = rls[nt * 16 + c];
#pragma unroll
            for (int r = 0; r < 4; ++r)
                Ps[w][quad * 4 + r][nt * 16 + c] = f2bf(__expf(s[r]) * rl);
        }
        // wave-private Ps: same-wave in-order DS ops, no block barrier needed
        bf16x8 ap0 = *(const bf16x8*)&Ps[w][c][quad * 8];
        bf16x8 ap1 = *(const bf16x8*)&Ps[w][c][32 + quad * 8];
#pragma unroll
        for (int dn = 0; dn < 4; ++dn) {
            acc[dn] = __builtin_amdgcn_mfma_f32_16x16x32_bf16(
                ap0, *(const bf16x8*)&Vst[dn * 16 + c][quad * 8], acc[dn], 0, 0, 0);
            acc[dn] = __builtin_amdgcn_mfma_f32_16x16x32_bf16(
                ap1, *(const bf16x8*)&Vst[dn * 16 + c][32 + quad * 8], acc[dn], 0, 0, 0);
        }
    }

#pragma unroll
    for (int dn = 0; dn < 4; ++dn)
#pragma unroll
        for (int r = 0; r < 4; ++r)
            atomicAdd(&out[((size_t)b * Nn + ibase + w * 16 + quad * 4 + r) * DHn
                           + dn * 16 + c], acc[dn][r]);
}

// ---------------------------------------------------------------------------
extern "C" void kernel_launch(void* const* d_in, const int* in_sizes, int n_in,
                              void* d_out, int out_size, void* d_ws, size_t ws_size,
                              hipStream_t stream)
{
    const float* x  = (const float*)d_in[0];
    const float* Wq = (const float*)d_in[1];
    const float* bq = (const float*)d_in[2];
    const float* Wk = (const float*)d_in[3];
    const float* bk = (const float*)d_in[4];
    const float* Wv = (const float*)d_in[5];
    const float* bv = (const float*)d_in[6];
    float* out = (float*)d_out;

    char* ws = (char*)d_ws;
    short* Qb = (short*)(ws);                            // 2 MB
    short* Kb = (short*)(ws + (size_t)(1 << 21));        // 2 MB
    short* Vt = (short*)(ws + (size_t)(2 << 21));        // 2 MB (transposed [b][d][j])
    short* Wt = (short*)(ws + (size_t)(3 << 21));        // 384 KB
    float* lv = (float*)(ws + (size_t)(3 << 21) + (1 << 19));  // 64 KB

    wt_kernel<<<dim3(192), dim3(256), 0, stream>>>(Wq, Wk, Wv, Wt);
    qkv_kernel<<<dim3(256), dim3(256), 0, stream>>>(x, Wt, bq, bk, bv, Qb, Kb, Vt);
    zero_kernel<<<dim3(1040), dim3(256), 0, stream>>>(out, lv);
    colsum_kernel<<<dim3(512), dim3(256), 0, stream>>>(Qb, Kb, lv);
    attnout_kernel<<<dim3(512), dim3(256), 0, stream>>>(Qb, Kb, Vt, lv, out);
}